// Round 2
// baseline (564.614 us; speedup 1.0000x reference)
//
#include <hip/hip_runtime.h>
#include <hip/hip_bf16.h>

// IntronsDecoder: h = BN(z@W1^T+b1); relu; pot = h@W2^T+b2; pot[:,3c]=0;
// out = softmax over groups of 3 consecutive columns.
// B=4096, N_IN=32, N_HID=128, N_OUT=30000, N_CLUST=10000.
//
// R4 changes vs R3 (548.3 us, store-width change proved a no-op):
//  - k_main is now PERSISTENT-B: 768 blocks (3/CU, LDS 48KB), each pinned to
//    one 128-row A slab (staged ONCE: 24.5 MB L2 traffic vs 640 MB) looping
//    over ~26 B tiles with double-buffered B prefetch. Prefetch is issued
//    after the barrier, compute runs, then the barrier's vmcnt(0) drain lands
//    AFTER compute -> B-load latency hides under the 16 MFMAs + epilogue.
//    All blocks sharing a rowblk have bid==rowblk (mod 32) -> same XCD: the A
//    slab and the out-row cache lines stay resident in one L2.
//  - k_cvt folded into k_hidden's grid (blocks 256..1505): one fewer dispatch.

typedef float  floatx4 __attribute__((ext_vector_type(4)));
typedef __bf16 bf16x8  __attribute__((ext_vector_type(8)));
typedef __bf16 bf16x4  __attribute__((ext_vector_type(4)));

struct F3 { float x, y, z; };   // 12B -> global_store_dwordx3

#define GLOBAL_AS __attribute__((address_space(1)))
#define LDS_AS    __attribute__((address_space(3)))

__device__ __forceinline__ void async16(void* lds, const void* g) {
    __builtin_amdgcn_global_load_lds((const GLOBAL_AS void*)g, (LDS_AS void*)lds, 16, 0, 0);
}

// ---- kernel 1: h = z@W1^T + b1 (+col sums/sumsq)  |  fused: W2 -> bf16 ----
// blocks 0..255: hidden GEMM, 16 rows each. blocks 256..1505: W2 convert,
// needed rows only (group members 1,2), pre-permuted into k_main's B order:
// permuted row rp = nb*32 + n  <-  source row nb*48 + 3*(n&15) + 1 + (n>>4).
__global__ __launch_bounds__(256) void k_hidden_cvt(const float* __restrict__ z,
                                                    const float* __restrict__ W1,
                                                    const float* __restrict__ b1,
                                                    float* __restrict__ h,
                                                    float* __restrict__ stats,
                                                    const float* __restrict__ w2,
                                                    __bf16* __restrict__ w2b) {
    const int bid = blockIdx.x;
    const int tid = threadIdx.x;
    if (bid >= 256) {   // ---- cvt part ----
        const int i  = (bid - 256) * 256 + tid;   // 8 elements each
        const int rp = i >> 4;            // permuted row 0..19999
        const int c  = i & 15;            // 8-float chunk within row
        const int nb = rp >> 5, n = rp & 31;
        const int src = nb * 48 + 3 * (n & 15) + 1 + (n >> 4);
        const float* s = w2 + (size_t)src * 128 + c * 8;
        floatx4 v0 = *(const floatx4*)s;
        floatx4 v1 = *(const floatx4*)(s + 4);
        bf16x8 o;
        o[0] = (__bf16)v0[0]; o[1] = (__bf16)v0[1]; o[2] = (__bf16)v0[2]; o[3] = (__bf16)v0[3];
        o[4] = (__bf16)v1[0]; o[5] = (__bf16)v1[1]; o[6] = (__bf16)v1[2]; o[7] = (__bf16)v1[3];
        *(bf16x8*)(w2b + (size_t)rp * 128 + c * 8) = o;
        return;
    }
    // ---- hidden part ----
    __shared__ float sW1[128 * 33];   // padded stride 33: conflict-free col reads
    __shared__ float sz[16 * 32];
    __shared__ float red[256];
    const int rb = bid * 16;
    for (int i = tid; i < 128 * 32; i += 256) sW1[(i >> 5) * 33 + (i & 31)] = W1[i];
    for (int i = tid; i < 16 * 32; i += 256) sz[i] = z[rb * 32 + i];
    __syncthreads();
    const int col = tid & 127, rh = tid >> 7;
    const float bias = b1[col];
    float lsum = 0.f, lsq = 0.f;
    for (int r = rh; r < 16; r += 2) {
        float acc = bias;
#pragma unroll
        for (int k = 0; k < 32; ++k) acc += sz[r * 32 + k] * sW1[col * 33 + k];
        h[(rb + r) * 128 + col] = acc;
        lsum += acc; lsq += acc * acc;
    }
    red[tid] = lsum; __syncthreads();
    if (rh == 0) atomicAdd(&stats[col], red[col] + red[col + 128]);
    __syncthreads();
    red[tid] = lsq; __syncthreads();
    if (rh == 0) atomicAdd(&stats[128 + col], red[col] + red[col + 128]);
}

// ---------------- kernel 2: batchnorm + relu + cast bf16 (x4 vectorized) --
__global__ __launch_bounds__(256) void k_norm(const float* __restrict__ h,
                                              const float* __restrict__ stats,
                                              const float* __restrict__ gamma,
                                              const float* __restrict__ beta,
                                              __bf16* __restrict__ hb) {
    const int idx = blockIdx.x * 256 + threadIdx.x;   // x4 elements; grid 512
    const int c0  = (idx * 4) & 127;
    floatx4 v = *(const floatx4*)(h + (size_t)idx * 4);
    bf16x4 o;
#pragma unroll
    for (int j = 0; j < 4; ++j) {
        const int col = c0 + j;
        const float mu  = stats[col] * (1.0f / 4096.0f);
        const float var = stats[128 + col] * (1.0f / 4096.0f) - mu * mu;
        const float sc  = gamma[col] * rsqrtf(var + 1e-3f);
        const float sh  = beta[col] - mu * sc;
        o[j] = (__bf16)fmaxf(v[j] * sc + sh, 0.0f);
    }
    *(bf16x4*)(hb + (size_t)idx * 4) = o;
}

// ---------------- kernel 3: fused GEMM + grouped softmax (persistent-B) ---
// 768 blocks = 32 rowblks x 24 slots. Block stages its 128-row A slab once
// (32KB), then iterates nblk = slot, slot+24, ... (26-27 tiles) with
// double-buffered B (2 x 8KB). Per iter: issue B[next] prefetch (post-
// barrier), 16 ds_read + 16 MFMA from A,B[cur], register epilogue (2 exp +
// rcp + dwordx3 store per group), then __syncthreads (vmcnt(0) drain lands
// after compute -> prefetch latency hidden).
// Chunk-XOR swizzle baked into the GLOBAL source index (LDS side of
// global_load_lds stays lane-contiguous): ds_read_b128 reads are 2-way (free).
__global__ __launch_bounds__(256, 3) void k_main(const __bf16* __restrict__ hb,
                                                 const __bf16* __restrict__ w2b,
                                                 const float* __restrict__ b2,
                                                 float* __restrict__ out) {
    __shared__ __align__(16) char smem[32768 + 2 * 8192];
    char* smemA = smem;               // 32KB: 128 rows x 256B (K=128 bf16)
    const int tid    = threadIdx.x;
    const int rowblk = blockIdx.x & 31;   // bid%32 -> bid%8 = rowblk%8: one XCD
    const int slot   = blockIdx.x >> 5;   // 0..23
    const int row0   = rowblk * 128;

    {   // A slab: rows row0..row0+127, full K -> contiguous 32KB (staged ONCE)
        const char* g = (const char*)(hb + (size_t)row0 * 128);
#pragma unroll
        for (int it = 0; it < 8; ++it) {
            int L = it * 256 + tid;
            int row = L >> 4, c = L & 15;
            int gc = (c & 8) | ((c ^ row) & 7);
            async16(smemA + L * 16, g + (row * 16 + gc) * 16);
        }
    }
    auto stageB = [&](char* dst, int nb) {   // 32 pre-permuted W2 rows, 8KB
        const char* g = (const char*)(w2b + (size_t)nb * 32 * 128);
#pragma unroll
        for (int it = 0; it < 2; ++it) {
            int L = it * 256 + tid;
            int n = L >> 4, c = L & 15;
            int gc = (c & 8) | ((c ^ n) & 7);
            async16(dst + L * 16, g + (n * 16 + gc) * 16);
        }
    };
    stageB(smem + 32768, slot);           // B[0] for first tile

    const int lane = tid & 63, w = tid >> 6;
    const int quad = lane >> 4, lr = lane & 15;
    const int cnt = (624 - slot) / 24 + 1;    // 27 for slot 0, else 26
    __syncthreads();                          // vmcnt(0): A + B[0] ready

    for (int i = 0; i < cnt; ++i) {
        const int nblk = slot + 24 * i;
        char* bcur  = smem + 32768 + ((i & 1) << 13);
        char* bnext = smem + 32768 + ((~i & 1) << 13);
        if (i + 1 < cnt) stageB(bnext, nblk + 24);   // in flight during compute

        const int cb = nblk * 48 + 3 * lr;    // this lane's group base column
        const float bb1 = b2[cb + 1];
        const float bb2 = b2[cb + 2];

        const floatx4 z4 = {0.f, 0.f, 0.f, 0.f};
        floatx4 acc[2][2] = {{z4, z4}, {z4, z4}};
#pragma unroll
        for (int ks = 0; ks < 4; ++ks) {      // k0 = ks*32
            const int cg = ks * 4 + quad;     // 16B chunk within a 256B row
            bf16x8 a[2], b[2];
#pragma unroll
            for (int s = 0; s < 2; ++s) {     // wave w owns rows w*32..+31
                int r  = w * 32 + s * 16 + lr;
                int ch = (cg & 8) | ((cg ^ r) & 7);
                a[s] = *(const bf16x8*)(smemA + r * 256 + ch * 16);
            }
#pragma unroll
            for (int t = 0; t < 2; ++t) {
                int n  = t * 16 + lr;
                int ch = (cg & 8) | ((cg ^ n) & 7);
                b[t] = *(const bf16x8*)(bcur + n * 256 + ch * 16);
            }
#pragma unroll
            for (int s = 0; s < 2; ++s)
#pragma unroll
                for (int t = 0; t < 2; ++t)
                    acc[s][t] = __builtin_amdgcn_mfma_f32_16x16x32_bf16(a[s], b[t], acc[s][t], 0, 0, 0);
        }

        // Pure-register epilogue. C/D: col = lr, row = quad*4+r. Lane lr's
        // acc[s][t][r] = pot(m, col 3lr+1+t) pre-bias; member 0 has pot=0.
#pragma unroll
        for (int s = 0; s < 2; ++s) {
#pragma unroll
            for (int r = 0; r < 4; ++r) {
                int m = row0 + w * 32 + s * 16 + quad * 4 + r;
                float v1  = __expf(acc[s][0][r] + bb1);
                float v2  = __expf(acc[s][1][r] + bb2);
                float inv = __builtin_amdgcn_rcpf(1.0f + v1 + v2);
                F3 o; o.x = inv; o.y = v1 * inv; o.z = v2 * inv;
                *(F3*)(out + (size_t)m * 30000 + cb) = o;
            }
        }
        __syncthreads();   // drains B[next] (hidden behind compute); syncs bcur readers
    }
}

extern "C" void kernel_launch(void* const* d_in, const int* in_sizes, int n_in,
                              void* d_out, int out_size, void* d_ws, size_t ws_size,
                              hipStream_t stream) {
    const float* z     = (const float*)d_in[0];
    const float* W1    = (const float*)d_in[1];
    const float* b1    = (const float*)d_in[2];
    const float* gamma = (const float*)d_in[3];
    const float* beta  = (const float*)d_in[4];
    const float* W2    = (const float*)d_in[5];
    const float* b2    = (const float*)d_in[6];
    // d_in[7] intron_clusters, d_in[8] first_indices: deterministic (j/3, 3c)
    float* out = (float*)d_out;

    char* ws = (char*)d_ws;
    float*  h     = (float*)ws;                       // 2 MB
    __bf16* hb    = (__bf16*)(ws + (2u << 20));       // 1 MB
    __bf16* w2b   = (__bf16*)(ws + (3u << 20));       // 5.12 MB (20000x128 bf16)
    float*  stats = (float*)(ws + (11u << 20));       // 1 KB (sum[128], sumsq[128])

    hipMemsetAsync(stats, 0, 256 * sizeof(float), stream);
    k_hidden_cvt<<<1506, 256, 0, stream>>>(z, W1, b1, h, stats, W2, w2b);
    k_norm<<<512, 256, 0, stream>>>(h, stats, gamma, beta, hb);
    k_main<<<768, 256, 0, stream>>>(hb, w2b, b2, out);
}

// Round 3
// 542.539 us; speedup vs baseline: 1.0407x; 1.0407x over previous
//
#include <hip/hip_runtime.h>
#include <hip/hip_bf16.h>

// IntronsDecoder: h = BN(z@W1^T+b1); relu; pot = h@W2^T+b2; pot[:,3c]=0;
// out = softmax over groups of 3 consecutive columns.
// B=4096, N_IN=32, N_HID=128, N_OUT=30000, N_CLUST=10000.
//
// R5: revert persistent-B (R4, 564.6us — per-iter vmcnt(0) barriers draining
// stores + 768-block TLP loss beat the A-amortization gain). Back to the
// proven ONE-SHOT block shape (R3, 548.3us), but with N widened 48 -> 96:
//  - each block: one stage (A 32KB + B 16KB), ONE barrier, 32 MFMA, 16 F3
//    stores, end. Staging bytes per output byte 1.63 -> 0.98; A traffic
//    640 -> 320 MB; stage-drains per CU 78 -> 39.
//  - LDS 48KB -> 3 blocks/CU (was 4): accepted, per-block compute doubles.
//  - grid (32, 313); last y covers only sub-tile u=0 (uniform ulim guard).

typedef float  floatx4 __attribute__((ext_vector_type(4)));
typedef __bf16 bf16x8  __attribute__((ext_vector_type(8)));
typedef __bf16 bf16x4  __attribute__((ext_vector_type(4)));

struct F3 { float x, y, z; };   // 12B -> global_store_dwordx3

#define GLOBAL_AS __attribute__((address_space(1)))
#define LDS_AS    __attribute__((address_space(3)))

__device__ __forceinline__ void async16(void* lds, const void* g) {
    __builtin_amdgcn_global_load_lds((const GLOBAL_AS void*)g, (LDS_AS void*)lds, 16, 0, 0);
}

// ---- kernel 1: h = z@W1^T + b1 (+col sums/sumsq)  |  fused: W2 -> bf16 ----
// blocks 0..255: hidden GEMM, 16 rows each. blocks 256..1505: W2 convert,
// needed rows only (group members 1,2), pre-permuted into k_main's B order:
// permuted row rp = nb*32 + n  <-  source row nb*48 + 3*(n&15) + 1 + (n>>4).
__global__ __launch_bounds__(256) void k_hidden_cvt(const float* __restrict__ z,
                                                    const float* __restrict__ W1,
                                                    const float* __restrict__ b1,
                                                    float* __restrict__ h,
                                                    float* __restrict__ stats,
                                                    const float* __restrict__ w2,
                                                    __bf16* __restrict__ w2b) {
    const int bid = blockIdx.x;
    const int tid = threadIdx.x;
    if (bid >= 256) {   // ---- cvt part ----
        const int i  = (bid - 256) * 256 + tid;   // 8 elements each
        const int rp = i >> 4;            // permuted row 0..19999
        const int c  = i & 15;            // 8-float chunk within row
        const int nb = rp >> 5, n = rp & 31;
        const int src = nb * 48 + 3 * (n & 15) + 1 + (n >> 4);
        const float* s = w2 + (size_t)src * 128 + c * 8;
        floatx4 v0 = *(const floatx4*)s;
        floatx4 v1 = *(const floatx4*)(s + 4);
        bf16x8 o;
        o[0] = (__bf16)v0[0]; o[1] = (__bf16)v0[1]; o[2] = (__bf16)v0[2]; o[3] = (__bf16)v0[3];
        o[4] = (__bf16)v1[0]; o[5] = (__bf16)v1[1]; o[6] = (__bf16)v1[2]; o[7] = (__bf16)v1[3];
        *(bf16x8*)(w2b + (size_t)rp * 128 + c * 8) = o;
        return;
    }
    // ---- hidden part ----
    __shared__ float sW1[128 * 33];   // padded stride 33: conflict-free col reads
    __shared__ float sz[16 * 32];
    __shared__ float red[256];
    const int rb = bid * 16;
    for (int i = tid; i < 128 * 32; i += 256) sW1[(i >> 5) * 33 + (i & 31)] = W1[i];
    for (int i = tid; i < 16 * 32; i += 256) sz[i] = z[rb * 32 + i];
    __syncthreads();
    const int col = tid & 127, rh = tid >> 7;
    const float bias = b1[col];
    float lsum = 0.f, lsq = 0.f;
    for (int r = rh; r < 16; r += 2) {
        float acc = bias;
#pragma unroll
        for (int k = 0; k < 32; ++k) acc += sz[r * 32 + k] * sW1[col * 33 + k];
        h[(rb + r) * 128 + col] = acc;
        lsum += acc; lsq += acc * acc;
    }
    red[tid] = lsum; __syncthreads();
    if (rh == 0) atomicAdd(&stats[col], red[col] + red[col + 128]);
    __syncthreads();
    red[tid] = lsq; __syncthreads();
    if (rh == 0) atomicAdd(&stats[128 + col], red[col] + red[col + 128]);
}

// ---------------- kernel 2: batchnorm + relu + cast bf16 (x4 vectorized) --
__global__ __launch_bounds__(256) void k_norm(const float* __restrict__ h,
                                              const float* __restrict__ stats,
                                              const float* __restrict__ gamma,
                                              const float* __restrict__ beta,
                                              __bf16* __restrict__ hb) {
    const int idx = blockIdx.x * 256 + threadIdx.x;   // x4 elements; grid 512
    const int c0  = (idx * 4) & 127;
    floatx4 v = *(const floatx4*)(h + (size_t)idx * 4);
    bf16x4 o;
#pragma unroll
    for (int j = 0; j < 4; ++j) {
        const int col = c0 + j;
        const float mu  = stats[col] * (1.0f / 4096.0f);
        const float var = stats[128 + col] * (1.0f / 4096.0f) - mu * mu;
        const float sc  = gamma[col] * rsqrtf(var + 1e-3f);
        const float sh  = beta[col] - mu * sc;
        o[j] = (__bf16)fmaxf(v[j] * sc + sh, 0.0f);
    }
    *(bf16x4*)(hb + (size_t)idx * 4) = o;
}

// ---------------- kernel 3: fused GEMM + grouped softmax (one-shot) -------
// block tile 128(M) x 96(N) = two 48-col sub-tiles (u=0,1); 256 threads =
// 4 waves; full K=128 staged once. LDS: A 32KB + B 16KB = 48KB -> 3 blk/CU.
// Chunk-XOR swizzle baked into the GLOBAL source index (LDS side of
// global_load_lds stays lane-contiguous): ds_read_b128 reads 2-way (free).
// w2b pre-permuted: B tile = linear 16KB slab (rows y*64 .. y*64+63).
__global__ __launch_bounds__(256, 3) void k_main(const __bf16* __restrict__ hb,
                                                 const __bf16* __restrict__ w2b,
                                                 const float* __restrict__ b2,
                                                 float* __restrict__ out) {
    __shared__ __align__(16) char smem[49152];
    char* smemA = smem;               // 32KB: 128 rows x 256B (K=128 bf16)
    char* smemB = smem + 32768;       // 16KB:  64 rows x 256B
    const int tid    = threadIdx.x;
    const int rowblk = blockIdx.x;    // 0..31 (fastest: same-A blocks on one XCD)
    const int y      = blockIdx.y;    // 0..312
    const int row0   = rowblk * 128;
    const int ulim   = (y == 312) ? 1 : 2;   // last tile: only sub-tile 0

    {   // A tile: rows row0..row0+127, full K -> contiguous 32KB slab
        const char* g = (const char*)(hb + (size_t)row0 * 128);
#pragma unroll
        for (int it = 0; it < 8; ++it) {
            int L = it * 256 + tid;
            int row = L >> 4, c = L & 15;
            int gc = (c & 8) | ((c ^ row) & 7);
            async16(smemA + L * 16, g + (row * 16 + gc) * 16);
        }
    }
    {   // B tile: 64 pre-permuted W2 rows, linear slab (col swizzle only)
        const char* g = (const char*)(w2b + (size_t)y * 64 * 128);
#pragma unroll
        for (int it = 0; it < 4; ++it) {
            int L = it * 256 + tid;
            int n = L >> 4, c = L & 15;
            int gc = (c & 8) | ((c ^ n) & 7);
            int nn = (n < 32 * ulim) ? n : (n - 32);   // clamp at y==312 (unused data)
            async16(smemB + L * 16, g + (nn * 16 + gc) * 16);
        }
    }

    const int lane = tid & 63, w = tid >> 6;
    const int quad = lane >> 4, lr = lane & 15;
    const int cb0 = y * 96 + 3 * lr;          // group base col, sub-tile u=0
    float bb1[2], bb2[2];
    bb1[0] = b2[cb0 + 1]; bb2[0] = b2[cb0 + 2];     // pre-barrier: latency hidden
    if (ulim > 1) { bb1[1] = b2[cb0 + 49]; bb2[1] = b2[cb0 + 50]; }
    else          { bb1[1] = 0.f;          bb2[1] = 0.f; }
    __syncthreads();                          // compiler emits vmcnt(0) drain here

    const floatx4 z4 = {0.f, 0.f, 0.f, 0.f};
    floatx4 acc[2][2][2];                     // [s][u][t]
#pragma unroll
    for (int s = 0; s < 2; ++s)
#pragma unroll
        for (int u = 0; u < 2; ++u)
#pragma unroll
            for (int t = 0; t < 2; ++t) acc[s][u][t] = z4;

#pragma unroll
    for (int ks = 0; ks < 4; ++ks) {          // k0 = ks*32
        const int cg = ks * 4 + quad;         // 16B chunk within a 256B row
        bf16x8 a[2], b[2][2];
#pragma unroll
        for (int s = 0; s < 2; ++s) {         // wave w owns rows w*32..+31
            int r  = w * 32 + s * 16 + lr;
            int ch = (cg & 8) | ((cg ^ r) & 7);
            a[s] = *(const bf16x8*)(smemA + r * 256 + ch * 16);
        }
#pragma unroll
        for (int u = 0; u < 2; ++u)
#pragma unroll
            for (int t = 0; t < 2; ++t) {
                int n  = u * 32 + t * 16 + lr;
                int ch = (cg & 8) | ((cg ^ n) & 7);
                b[u][t] = *(const bf16x8*)(smemB + n * 256 + ch * 16);
            }
#pragma unroll
        for (int s = 0; s < 2; ++s)
#pragma unroll
            for (int u = 0; u < 2; ++u)
#pragma unroll
                for (int t = 0; t < 2; ++t)
                    acc[s][u][t] = __builtin_amdgcn_mfma_f32_16x16x32_bf16(a[s], b[u][t], acc[s][u][t], 0, 0, 0);
    }

    // Pure-register epilogue. C/D: col = lr, row = quad*4+r. Lane lr's
    // acc[s][u][t][r] = pot(m, col (2y+u)*48 + 3lr+1+t) pre-bias; member 0
    // is pinned to pot=0 -> p=1. One dwordx3 store per group.
#pragma unroll
    for (int s = 0; s < 2; ++s) {
#pragma unroll
        for (int u = 0; u < 2; ++u) {
            if (u < ulim) {                   // uniform per block
#pragma unroll
                for (int r = 0; r < 4; ++r) {
                    int m = row0 + w * 32 + s * 16 + quad * 4 + r;
                    float v1  = __expf(acc[s][u][0][r] + bb1[u]);
                    float v2  = __expf(acc[s][u][1][r] + bb2[u]);
                    float inv = __builtin_amdgcn_rcpf(1.0f + v1 + v2);
                    F3 o; o.x = inv; o.y = v1 * inv; o.z = v2 * inv;
                    *(F3*)(out + (size_t)m * 30000 + cb0 + u * 48) = o;
                }
            }
        }
    }
}

extern "C" void kernel_launch(void* const* d_in, const int* in_sizes, int n_in,
                              void* d_out, int out_size, void* d_ws, size_t ws_size,
                              hipStream_t stream) {
    const float* z     = (const float*)d_in[0];
    const float* W1    = (const float*)d_in[1];
    const float* b1    = (const float*)d_in[2];
    const float* gamma = (const float*)d_in[3];
    const float* beta  = (const float*)d_in[4];
    const float* W2    = (const float*)d_in[5];
    const float* b2    = (const float*)d_in[6];
    // d_in[7] intron_clusters, d_in[8] first_indices: deterministic (j/3, 3c)
    float* out = (float*)d_out;

    char* ws = (char*)d_ws;
    float*  h     = (float*)ws;                       // 2 MB
    __bf16* hb    = (__bf16*)(ws + (2u << 20));       // 1 MB
    __bf16* w2b   = (__bf16*)(ws + (3u << 20));       // 5.12 MB (20000x128 bf16)
    float*  stats = (float*)(ws + (11u << 20));       // 1 KB (sum[128], sumsq[128])

    hipMemsetAsync(stats, 0, 256 * sizeof(float), stream);
    k_hidden_cvt<<<1506, 256, 0, stream>>>(z, W1, b1, h, stats, W2, w2b);
    k_norm<<<512, 256, 0, stream>>>(h, stats, gamma, beta, hb);
    dim3 grid(32, 313);
    k_main<<<grid, 256, 0, stream>>>(hb, w2b, b2, out);
}